// Round 11
// baseline (215.316 us; speedup 1.0000x reference)
//
#include <hip/hip_runtime.h>
#include <cstdint>
#include <cstddef>

#define THREADS 256
#define NB 8   // partial-sum blocks per group

typedef float f32x4 __attribute__((ext_vector_type(4)));
typedef __bf16 bf16x8 __attribute__((ext_vector_type(8)));
typedef __bf16 bf16x4 __attribute__((ext_vector_type(4)));

// ---------- async global->LDS, 16B per lane, wave-uniform LDS base ----------
__device__ __forceinline__ void gload_lds16(const void* g, void* l) {
    auto gp = (const __attribute__((address_space(1))) unsigned int*)(unsigned long long)(uintptr_t)g;
    auto lp = (__attribute__((address_space(3))) unsigned int*)(unsigned int)(uintptr_t)l;
    __builtin_amdgcn_global_load_lds(gp, lp, 16, 0, 0);
}

// ---------- zero the gamma scratch ----------
__global__ void zero_gamma(unsigned int* p) {
    if (threadIdx.x < 16) p[threadIdx.x] = 0u;
}

// ---------- phase 1: per-(group,block) partial sums, deterministic ----------
__global__ void group_partial_sums(const float* __restrict__ W, float* __restrict__ partials,
                                   int elems_per_group) {
    const int g = blockIdx.y, b = blockIdx.x;
    const int tid = threadIdx.x;
    const int chunk4 = elems_per_group / (4 * NB);
    const float* base = W + (size_t)g * elems_per_group + (size_t)b * chunk4 * 4;
    float s = 0.f;
    for (int i = tid; i < chunk4; i += THREADS) {
        f32x4 v = *reinterpret_cast<const f32x4*>(base + 4 * (size_t)i);
        s += (v[0] + v[1]) + (v[2] + v[3]);
    }
    __shared__ float red[THREADS];
    red[tid] = s;
    __syncthreads();
    for (int off = THREADS / 2; off > 0; off >>= 1) {
        if (tid < off) red[tid] += red[tid + off];
        __syncthreads();
    }
    if (tid == 0) partials[g * NB + b] = red[0];
}

// ---------- phase 2: binarize each chunk using the group mean ----------
__global__ void binarize_apply(const float* __restrict__ W, __bf16* __restrict__ Wb,
                               const float* __restrict__ partials,
                               int elems_per_group, int tail_elems) {
    const int g = blockIdx.y, b = blockIdx.x;
    const int tid = threadIdx.x;
    if (g == 5) {
        if (b != 0) return;
        __bf16* og = Wb + (size_t)5 * elems_per_group;
        for (int i = tid; i < tail_elems; i += THREADS) og[i] = (__bf16)0.f;
        return;
    }
    float total = 0.f;
#pragma unroll
    for (int j = 0; j < NB; ++j) total += partials[g * NB + j];
    const float mean = total / (float)elems_per_group;

    const int chunk4 = elems_per_group / (4 * NB);
    const size_t off0 = (size_t)g * elems_per_group + (size_t)b * chunk4 * 4;
    const float* base = W + off0;
    __bf16* ob = Wb + off0;
    for (int i = tid; i < chunk4; i += THREADS) {
        f32x4 v = *reinterpret_cast<const f32x4*>(base + 4 * (size_t)i);
        bf16x4 o;
#pragma unroll
        for (int j = 0; j < 4; ++j) {
            const float z = v[j] - mean;
            o[j] = (__bf16)((z > 0.f) ? 1.f : ((z < 0.f) ? -1.f : 0.f));
        }
        *reinterpret_cast<bf16x4*>(ob + 4 * (size_t)i) = o;
    }
}

// ---------- f32 -> bf16 vectorized convert ----------
__global__ void cvt_f32_bf16(const float* __restrict__ in, __bf16* __restrict__ ot, int n4) {
    int i = blockIdx.x * blockDim.x + threadIdx.x;
    if (i >= n4) return;
    f32x4 v = *reinterpret_cast<const f32x4*>(in + 4 * (size_t)i);
    bf16x4 o;
    o[0] = (__bf16)v[0]; o[1] = (__bf16)v[1]; o[2] = (__bf16)v[2]; o[3] = (__bf16)v[3];
    *reinterpret_cast<bf16x4*>(ot + 4 * (size_t)i) = o;
}

// ================= GEMM1: y1[m,n] = xb[m,:]*W1b[n,:] + b1[n], RAW bf16 out ==
// R3 proven structure (BM=256 BN=256 BK=64, 8 waves 2Mx4N, 2-phase prefetch,
// gload_lds A+B, T2 XOR swizzle, XCD bijective swizzle) + R9/R10 proven
// SWAPPED mfma(bfv, af): lane's 4 acc regs = 4 consecutive output cols ->
// packed bf16x4 8B stores (no 2B scatter / write amplification).
__global__ __launch_bounds__(512, 2)
void gemm1_bt(const __bf16* __restrict__ A, const __bf16* __restrict__ Bw,
              const float* __restrict__ bias, __bf16* __restrict__ outp,
              unsigned int* __restrict__ gmax, int M, int N, int K,
              int GN, int nwg) {
    constexpr int BM = 256, BN_ = 256, BK = 64, NF = 4;
    constexpr int ABYTES = BM * BK * 2;        // 32768
    constexpr int BBYTES = BN_ * BK * 2;       // 32768
    __shared__ __attribute__((aligned(16))) char lds[2 * (ABYTES + BBYTES)];

    const int tid = threadIdx.x;
    const int wave = tid >> 6, lane = tid & 63;
    const int l15 = lane & 15, l4 = lane >> 4;
    const int wr = wave >> 2, wc = wave & 3;

    const int cpx = nwg >> 3;
    const int orig = (blockIdx.x & 7) * cpx + (blockIdx.x >> 3);
    const int bm = orig / GN, bn = orig % GN;

    const __bf16* Ab = A + (size_t)bm * BM * K;
    const __bf16* Bb = Bw + (size_t)bn * BN_ * K;
    const int NT = K / BK;

    f32x4 acc[8][NF];
#pragma unroll
    for (int m = 0; m < 8; ++m)
#pragma unroll
        for (int n = 0; n < NF; ++n)
            acc[m][n] = f32x4{0.f, 0.f, 0.f, 0.f};

    auto STAGE = [&](int t) {
        const int k0 = t * BK;
        char* ab = lds + (t & 1) * (ABYTES + BBYTES);
        char* bb = ab + ABYTES;
#pragma unroll
        for (int j = 0; j < 4; ++j) {
            const int q = j * 8192 + tid * 16;
            const int lr = q >> 7;
            const int s = ((q >> 4) & 7) ^ (lr & 7);
            gload_lds16(Ab + (size_t)lr * K + k0 + s * 8, ab + q);
        }
#pragma unroll
        for (int j = 0; j < 4; ++j) {
            const int q = j * 8192 + tid * 16;
            const int lr = q >> 7;
            const int s = ((q >> 4) & 7) ^ (lr & 7);
            gload_lds16(Bb + (size_t)lr * K + k0 + s * 8, bb + q);
        }
    };

    STAGE(0);
    asm volatile("s_waitcnt vmcnt(0)" ::: "memory");
    __syncthreads();

    for (int t = 0; t < NT; ++t) {
        if (t + 1 < NT) STAGE(t + 1);
        const char* ab = lds + (t & 1) * (ABYTES + BBYTES);
        const char* bb = ab + ABYTES;
#pragma unroll
        for (int kk = 0; kk < 2; ++kk) {
            bf16x8 af[8], bfv[NF];
#pragma unroll
            for (int m = 0; m < 8; ++m) {
                const int r = wr * 128 + m * 16 + l15;
                const int sp = (kk * 4 + l4) ^ (r & 7);
                af[m] = *reinterpret_cast<const bf16x8*>(ab + r * 128 + sp * 16);
            }
#pragma unroll
            for (int n = 0; n < NF; ++n) {
                const int r = wc * 64 + n * 16 + l15;
                const int sp = (kk * 4 + l4) ^ (r & 7);
                bfv[n] = *reinterpret_cast<const bf16x8*>(bb + r * 128 + sp * 16);
            }
#pragma unroll
            for (int m = 0; m < 8; ++m)
#pragma unroll
                for (int n = 0; n < NF; ++n)
                    acc[m][n] = __builtin_amdgcn_mfma_f32_16x16x32_bf16(
                        bfv[n], af[m], acc[m][n], 0, 0, 0);   // SWAPPED
        }
        asm volatile("s_waitcnt vmcnt(0)" ::: "memory");
        __syncthreads();
    }

    // epilogue (swapped): row = rowb+m*16+l15, col = colb+n*16+l4*4+r
    const int rowb = bm * BM + wr * 128;
    const int colb = bn * BN_ + wc * 64;
    float lmax = 0.f;
#pragma unroll
    for (int n = 0; n < NF; ++n) {
        const f32x4 bv = *reinterpret_cast<const f32x4*>(bias + colb + n * 16 + l4 * 4);
#pragma unroll
        for (int m = 0; m < 8; ++m) {
            const int row = rowb + m * 16 + l15;
            bf16x4 o;
#pragma unroll
            for (int r = 0; r < 4; ++r) {
                const float v = acc[m][n][r] + bv[r];
                lmax = fmaxf(lmax, fabsf(v));
                o[r] = (__bf16)v;
            }
            *reinterpret_cast<bf16x4*>(
                &outp[(size_t)row * N + colb + n * 16 + l4 * 4]) = o;
        }
    }
#pragma unroll
    for (int off = 32; off > 0; off >>= 1)
        lmax = fmaxf(lmax, __shfl_down(lmax, off, 64));
    float* wredmax = (float*)lds;
    if (lane == 0) wredmax[wave] = lmax;
    __syncthreads();
    if (tid == 0) {
        float bmax = wredmax[0];
#pragma unroll
        for (int w = 1; w < 8; ++w) bmax = fmaxf(bmax, wredmax[w]);
        atomicMax(gmax + (bm * BM) / 4096, __float_as_uint(bmax));
    }
}

// ====== GEMM2 + fused quant/GELU on the A-path (kills the quant_gelu pass) ==
// out_raw[m,n] = sum_k gelu(clip(y1raw[m,k]*s1)) * W2b[n,k] + b2[n]
// A (y1 raw bf16) is reg-staged: LOADA(t+1) issued BEFORE compute(t) (T14
// issue-early), after vmcnt(0) apply scale+clip+erf-gelu in regs, swizzled
// ds_write. s1 = 128/(gamma1[group]+eps) is one scalar per block (256-row
// tile sits in one 4096-row quant group). B stays gload_lds (L2-resident).
// Same swapped-MFMA wide-store epilogue; gamma2 via atomicMax.
__global__ __launch_bounds__(512, 2)
void gemm2_fused(const __bf16* __restrict__ A, const __bf16* __restrict__ Bw,
                 const float* __restrict__ bias, float* __restrict__ outp,
                 const unsigned int* __restrict__ g1bits,
                 unsigned int* __restrict__ gmax, int M, int N, int K,
                 int GN, int nwg) {
    constexpr int BM = 256, BN_ = 128, BK = 64, NF = 2;
    constexpr int ABYTES = BM * BK * 2;        // 32768
    constexpr int BBYTES = BN_ * BK * 2;       // 16384
    __shared__ __attribute__((aligned(16))) char lds[2 * (ABYTES + BBYTES)];

    const int tid = threadIdx.x;
    const int wave = tid >> 6, lane = tid & 63;
    const int l15 = lane & 15, l4 = lane >> 4;
    const int wr = wave >> 2, wc = wave & 3;

    const int cpx = nwg >> 3;
    const int orig = (blockIdx.x & 7) * cpx + (blockIdx.x >> 3);
    const int bm = orig / GN, bn = orig % GN;

    const float s1 = 128.0f / (__uint_as_float(g1bits[bm >> 4]) + 1e-5f);

    const int arow = tid >> 1;                 // A row this thread stages
    const int ach = tid & 1;                   // which 32-col half of BK
    const __bf16* Aptr = A + (size_t)(bm * BM + arow) * K + ach * 32;
    const __bf16* Bb = Bw + (size_t)bn * BN_ * K;
    const int NT = K / BK;

    f32x4 acc[8][NF];
#pragma unroll
    for (int m = 0; m < 8; ++m)
#pragma unroll
        for (int n = 0; n < NF; ++n)
            acc[m][n] = f32x4{0.f, 0.f, 0.f, 0.f};

    bf16x8 areg[4];
    auto LOADA = [&](int t) {
        const __bf16* p = Aptr + t * BK;
#pragma unroll
        for (int j = 0; j < 4; ++j)
            areg[j] = *reinterpret_cast<const bf16x8*>(p + j * 8);
    };
    auto GELU_WRITEA = [&](int t) {   // quant+gelu in regs, swizzled ds_write
        char* ab = lds + (t & 1) * (ABYTES + BBYTES);
#pragma unroll
        for (int j = 0; j < 4; ++j) {
            bf16x8 w;
#pragma unroll
            for (int e = 0; e < 8; ++e) {
                float f = (float)areg[j][e] * s1;
                f = fminf(fmaxf(f, -128.0f + 1e-5f), 128.0f - 1e-5f);
                w[e] = (__bf16)(0.5f * f * (1.0f + erff(f * 0.70710678118654752f)));
            }
            const int s = ach * 4 + j;         // logical 16B slot
            *reinterpret_cast<bf16x8*>(
                ab + arow * 128 + ((s ^ (arow & 7)) << 4)) = w;
        }
    };
    auto STAGEB = [&](int t) {
        char* bb = lds + (t & 1) * (ABYTES + BBYTES) + ABYTES;
#pragma unroll
        for (int j = 0; j < 2; ++j) {
            const int q = j * 8192 + tid * 16;
            const int lr = q >> 7;
            const int s = ((q >> 4) & 7) ^ (lr & 7);
            gload_lds16(Bb + (size_t)lr * K + t * BK + s * 8, bb + q);
        }
    };

    LOADA(0); STAGEB(0);
    asm volatile("s_waitcnt vmcnt(0)" ::: "memory");
    GELU_WRITEA(0);
    __syncthreads();

    for (int t = 0; t < NT; ++t) {
        if (t + 1 < NT) { LOADA(t + 1); STAGEB(t + 1); }   // issue early
        const char* ab = lds + (t & 1) * (ABYTES + BBYTES);
        const char* bb = ab + ABYTES;
#pragma unroll
        for (int kk = 0; kk < 2; ++kk) {
            bf16x8 af[8], bfv[NF];
#pragma unroll
            for (int m = 0; m < 8; ++m) {
                const int r = wr * 128 + m * 16 + l15;
                const int sp = (kk * 4 + l4) ^ (r & 7);
                af[m] = *reinterpret_cast<const bf16x8*>(ab + r * 128 + sp * 16);
            }
#pragma unroll
            for (int n = 0; n < NF; ++n) {
                const int r = wc * 32 + n * 16 + l15;
                const int sp = (kk * 4 + l4) ^ (r & 7);
                bfv[n] = *reinterpret_cast<const bf16x8*>(bb + r * 128 + sp * 16);
            }
#pragma unroll
            for (int m = 0; m < 8; ++m)
#pragma unroll
                for (int n = 0; n < NF; ++n)
                    acc[m][n] = __builtin_amdgcn_mfma_f32_16x16x32_bf16(
                        bfv[n], af[m], acc[m][n], 0, 0, 0);   // SWAPPED
        }
        asm volatile("s_waitcnt vmcnt(0)" ::: "memory");      // t+1 A regs + B lds
        if (t + 1 < NT) GELU_WRITEA(t + 1);                   // write late
        __syncthreads();
    }

    // epilogue (swapped): f32x4 16B stores -> full 64B sectors per l4-quad
    const int rowb = bm * BM + wr * 128;
    const int colb = bn * BN_ + wc * 32;
    float lmax = 0.f;
#pragma unroll
    for (int n = 0; n < NF; ++n) {
        const f32x4 bv = *reinterpret_cast<const f32x4*>(bias + colb + n * 16 + l4 * 4);
#pragma unroll
        for (int m = 0; m < 8; ++m) {
            const int row = rowb + m * 16 + l15;
            f32x4 o;
#pragma unroll
            for (int r = 0; r < 4; ++r) {
                o[r] = acc[m][n][r] + bv[r];
                lmax = fmaxf(lmax, fabsf(o[r]));
            }
            *reinterpret_cast<f32x4*>(
                &outp[(size_t)row * N + colb + n * 16 + l4 * 4]) = o;
        }
    }
#pragma unroll
    for (int off = 32; off > 0; off >>= 1)
        lmax = fmaxf(lmax, __shfl_down(lmax, off, 64));
    float* wredmax = (float*)lds;
    if (lane == 0) wredmax[wave] = lmax;
    __syncthreads();
    if (tid == 0) {
        float bmax = wredmax[0];
#pragma unroll
        for (int w = 1; w < 8; ++w) bmax = fmaxf(bmax, wredmax[w]);
        atomicMax(gmax + (bm * BM) / 4096, __float_as_uint(bmax));
    }
}

// ---------- in-place absmax quantize of f32 output ----------
__global__ void final_scale(float* __restrict__ y, const unsigned int* __restrict__ gbits,
                            int perg4, int n4) {
    int i = blockIdx.x * blockDim.x + threadIdx.x;
    if (i >= n4) return;
    const int g = i / perg4;
    const float gamma = __uint_as_float(gbits[g]);
    const float s = 128.0f / (gamma + 1e-5f);
    f32x4 v = *reinterpret_cast<const f32x4*>(y + 4 * (size_t)i);
    f32x4 o;
#pragma unroll
    for (int j = 0; j < 4; ++j)
        o[j] = fminf(fmaxf(v[j] * s, -128.0f + 1e-5f), 128.0f - 1e-5f);
    *reinterpret_cast<f32x4*>(y + 4 * (size_t)i) = o;
}

extern "C" void kernel_launch(void* const* d_in, const int* in_sizes, int n_in,
                              void* d_out, int out_size, void* d_ws, size_t ws_size,
                              hipStream_t stream) {
    const float* x  = (const float*)d_in[0];   // (10,2048,384)
    const float* W1 = (const float*)d_in[1];   // (1536,384)
    const float* b1 = (const float*)d_in[2];   // (1536,)
    const float* W2 = (const float*)d_in[3];   // (384,1536)
    const float* b2 = (const float*)d_in[4];   // (384,)
    float* out = (float*)d_out;                // (10,2048,384) f32

    const int BB = 10, TT = 2048, C = 384, H = 1536;
    const int M = BB * TT;                     // 20480; act group = 4096 rows

    const int gs1 = H / 5;
    const int gs2 = C / 5;
    const int epg1 = gs1 * C;
    const int epg2 = gs2 * H;
    const int tail1 = (H - 5 * gs1) * C;
    const int tail2 = (C - 5 * gs2) * H;

    const size_t szW1b = (size_t)H * C * 2;
    const size_t szW2b = (size_t)C * H * 2;
    const size_t szXb  = (size_t)M * C * 2;
    const size_t szY1  = (size_t)M * H * 2;

    char* p = (char*)d_ws;
    __bf16* W1b = (__bf16*)p; p += szW1b;
    __bf16* W2b = (__bf16*)p; p += szW2b;
    __bf16* xb  = (__bf16*)p; p += szXb;
    __bf16* y1  = (__bf16*)p; p += szY1;      // RAW y1 (pre-quant, pre-gelu)
    unsigned int* gamma = (unsigned int*)p; p += 64;
    float* psums = (float*)p; p += 2 * 5 * NB * 4;
    if ((size_t)(p - (char*)d_ws) > ws_size) return;

    zero_gamma<<<1, 64, 0, stream>>>(gamma);

    group_partial_sums<<<dim3(NB, 5), THREADS, 0, stream>>>(W1, psums, epg1);
    group_partial_sums<<<dim3(NB, 5), THREADS, 0, stream>>>(W2, psums + 5 * NB, epg2);
    binarize_apply<<<dim3(NB, 6), THREADS, 0, stream>>>(W1, W1b, psums, epg1, tail1);
    binarize_apply<<<dim3(NB, 6), THREADS, 0, stream>>>(W2, W2b, psums + 5 * NB, epg2, tail2);

    cvt_f32_bf16<<<(M * C / 4 + THREADS - 1) / THREADS, THREADS, 0, stream>>>(x, xb, M * C / 4);

    // GEMM1: 20480x1536x384, raw y1 out. grid 80*6 = 480 (%8==0)
    gemm1_bt<<<480, 512, 0, stream>>>(
        xb, W1b, b1, y1, gamma, M, H, C, H / 256, 480);

    // GEMM2 (fused quant+gelu on A): 20480x384x1536. grid 80*3 = 240 (%8==0)
    gemm2_fused<<<240, 512, 0, stream>>>(
        y1, W2b, b2, out, gamma, gamma + 5, M, C, H, C / 128, 240);

    final_scale<<<(M * C / 4 + THREADS - 1) / THREADS, THREADS, 0, stream>>>(
        out, gamma + 5, (M / 5) * C / 4, M * C / 4);
}

// Round 12
// 149.104 us; speedup vs baseline: 1.4441x; 1.4441x over previous
//
#include <hip/hip_runtime.h>
#include <cstdint>
#include <cstddef>

#define THREADS 256
#define NB 8   // partial-sum blocks per group

typedef float f32x4 __attribute__((ext_vector_type(4)));
typedef __bf16 bf16x8 __attribute__((ext_vector_type(8)));
typedef __bf16 bf16x4 __attribute__((ext_vector_type(4)));

// ---------- async global->LDS, 16B per lane, wave-uniform LDS base ----------
__device__ __forceinline__ void gload_lds16(const void* g, void* l) {
    auto gp = (const __attribute__((address_space(1))) unsigned int*)(unsigned long long)(uintptr_t)g;
    auto lp = (__attribute__((address_space(3))) unsigned int*)(unsigned int)(uintptr_t)l;
    __builtin_amdgcn_global_load_lds(gp, lp, 16, 0, 0);
}

// ---------- exact-GELU with fast erf (Abramowitz-Stegun 7.1.26) ------------
// |erf err| <= 1.5e-7 absolute -> gelu err ~2e-5 at |f|<=128, negligible vs
// the bf16 rounding already in the pipeline. ~15 VALU ops vs libm erff ~84
// (measured R11: 101us VALU for 94.4M evals).
__device__ __forceinline__ float gelu_fast(float f) {
    const float z = f * 0.70710678118654752f;
    const float az = fabsf(z);
    const float t = __builtin_amdgcn_rcpf(fmaf(0.3275911f, az, 1.0f));
    float poly = fmaf(1.061405429f, t, -1.453152027f);
    poly = fmaf(poly, t, 1.421413741f);
    poly = fmaf(poly, t, -0.284496736f);
    poly = fmaf(poly, t, 0.254829592f);
    poly *= t;
    const float e = __builtin_amdgcn_exp2f(-az * az * 1.44269504088896f);
    float erfv = fmaf(-poly, e, 1.0f);
    erfv = copysignf(erfv, z);
    return 0.5f * f * (1.0f + erfv);
}

// ---------- zero the gamma scratch ----------
__global__ void zero_gamma(unsigned int* p) {
    if (threadIdx.x < 16) p[threadIdx.x] = 0u;
}

// ---------- phase 1: per-(group,block) partial sums, deterministic ----------
__global__ void group_partial_sums(const float* __restrict__ W, float* __restrict__ partials,
                                   int elems_per_group) {
    const int g = blockIdx.y, b = blockIdx.x;
    const int tid = threadIdx.x;
    const int chunk4 = elems_per_group / (4 * NB);
    const float* base = W + (size_t)g * elems_per_group + (size_t)b * chunk4 * 4;
    float s = 0.f;
    for (int i = tid; i < chunk4; i += THREADS) {
        f32x4 v = *reinterpret_cast<const f32x4*>(base + 4 * (size_t)i);
        s += (v[0] + v[1]) + (v[2] + v[3]);
    }
    __shared__ float red[THREADS];
    red[tid] = s;
    __syncthreads();
    for (int off = THREADS / 2; off > 0; off >>= 1) {
        if (tid < off) red[tid] += red[tid + off];
        __syncthreads();
    }
    if (tid == 0) partials[g * NB + b] = red[0];
}

// ---------- phase 2: binarize each chunk using the group mean ----------
__global__ void binarize_apply(const float* __restrict__ W, __bf16* __restrict__ Wb,
                               const float* __restrict__ partials,
                               int elems_per_group, int tail_elems) {
    const int g = blockIdx.y, b = blockIdx.x;
    const int tid = threadIdx.x;
    if (g == 5) {
        if (b != 0) return;
        __bf16* og = Wb + (size_t)5 * elems_per_group;
        for (int i = tid; i < tail_elems; i += THREADS) og[i] = (__bf16)0.f;
        return;
    }
    float total = 0.f;
#pragma unroll
    for (int j = 0; j < NB; ++j) total += partials[g * NB + j];
    const float mean = total / (float)elems_per_group;

    const int chunk4 = elems_per_group / (4 * NB);
    const size_t off0 = (size_t)g * elems_per_group + (size_t)b * chunk4 * 4;
    const float* base = W + off0;
    __bf16* ob = Wb + off0;
    for (int i = tid; i < chunk4; i += THREADS) {
        f32x4 v = *reinterpret_cast<const f32x4*>(base + 4 * (size_t)i);
        bf16x4 o;
#pragma unroll
        for (int j = 0; j < 4; ++j) {
            const float z = v[j] - mean;
            o[j] = (__bf16)((z > 0.f) ? 1.f : ((z < 0.f) ? -1.f : 0.f));
        }
        *reinterpret_cast<bf16x4*>(ob + 4 * (size_t)i) = o;
    }
}

// ---------- f32 -> bf16 vectorized convert ----------
__global__ void cvt_f32_bf16(const float* __restrict__ in, __bf16* __restrict__ ot, int n4) {
    int i = blockIdx.x * blockDim.x + threadIdx.x;
    if (i >= n4) return;
    f32x4 v = *reinterpret_cast<const f32x4*>(in + 4 * (size_t)i);
    bf16x4 o;
    o[0] = (__bf16)v[0]; o[1] = (__bf16)v[1]; o[2] = (__bf16)v[2]; o[3] = (__bf16)v[3];
    *reinterpret_cast<bf16x4*>(ot + 4 * (size_t)i) = o;
}

// ================= GEMM1: y1[m,n] = xb[m,:]*W1b[n,:] + b1[n], bf16 out ======
// R3 proven structure (BM=256 BN=256 BK=64, 8 waves 2Mx4N, 2-phase prefetch,
// gload_lds A+B, T2 XOR swizzle, XCD bijective swizzle) + proven SWAPPED
// mfma(bfv, af): lane's 4 acc regs = 4 consecutive output cols -> packed
// bf16x4 8B stores (WRITE_SIZE 102->73MB measured R9/R10).
__global__ __launch_bounds__(512, 2)
void gemm1_bt(const __bf16* __restrict__ A, const __bf16* __restrict__ Bw,
              const float* __restrict__ bias, __bf16* __restrict__ outp,
              unsigned int* __restrict__ gmax, int M, int N, int K,
              int GN, int nwg) {
    constexpr int BM = 256, BN_ = 256, BK = 64, NF = 4;
    constexpr int ABYTES = BM * BK * 2;
    constexpr int BBYTES = BN_ * BK * 2;
    __shared__ __attribute__((aligned(16))) char lds[2 * (ABYTES + BBYTES)];

    const int tid = threadIdx.x;
    const int wave = tid >> 6, lane = tid & 63;
    const int l15 = lane & 15, l4 = lane >> 4;
    const int wr = wave >> 2, wc = wave & 3;

    const int cpx = nwg >> 3;
    const int orig = (blockIdx.x & 7) * cpx + (blockIdx.x >> 3);
    const int bm = orig / GN, bn = orig % GN;

    const __bf16* Ab = A + (size_t)bm * BM * K;
    const __bf16* Bb = Bw + (size_t)bn * BN_ * K;
    const int NT = K / BK;

    f32x4 acc[8][NF];
#pragma unroll
    for (int m = 0; m < 8; ++m)
#pragma unroll
        for (int n = 0; n < NF; ++n)
            acc[m][n] = f32x4{0.f, 0.f, 0.f, 0.f};

    auto STAGE = [&](int t) {
        const int k0 = t * BK;
        char* ab = lds + (t & 1) * (ABYTES + BBYTES);
        char* bb = ab + ABYTES;
#pragma unroll
        for (int j = 0; j < 4; ++j) {
            const int q = j * 8192 + tid * 16;
            const int lr = q >> 7;
            const int s = ((q >> 4) & 7) ^ (lr & 7);
            gload_lds16(Ab + (size_t)lr * K + k0 + s * 8, ab + q);
        }
#pragma unroll
        for (int j = 0; j < 4; ++j) {
            const int q = j * 8192 + tid * 16;
            const int lr = q >> 7;
            const int s = ((q >> 4) & 7) ^ (lr & 7);
            gload_lds16(Bb + (size_t)lr * K + k0 + s * 8, bb + q);
        }
    };

    STAGE(0);
    asm volatile("s_waitcnt vmcnt(0)" ::: "memory");
    __syncthreads();

    for (int t = 0; t < NT; ++t) {
        if (t + 1 < NT) STAGE(t + 1);
        const char* ab = lds + (t & 1) * (ABYTES + BBYTES);
        const char* bb = ab + ABYTES;
#pragma unroll
        for (int kk = 0; kk < 2; ++kk) {
            bf16x8 af[8], bfv[NF];
#pragma unroll
            for (int m = 0; m < 8; ++m) {
                const int r = wr * 128 + m * 16 + l15;
                const int sp = (kk * 4 + l4) ^ (r & 7);
                af[m] = *reinterpret_cast<const bf16x8*>(ab + r * 128 + sp * 16);
            }
#pragma unroll
            for (int n = 0; n < NF; ++n) {
                const int r = wc * 64 + n * 16 + l15;
                const int sp = (kk * 4 + l4) ^ (r & 7);
                bfv[n] = *reinterpret_cast<const bf16x8*>(bb + r * 128 + sp * 16);
            }
#pragma unroll
            for (int m = 0; m < 8; ++m)
#pragma unroll
                for (int n = 0; n < NF; ++n)
                    acc[m][n] = __builtin_amdgcn_mfma_f32_16x16x32_bf16(
                        bfv[n], af[m], acc[m][n], 0, 0, 0);   // SWAPPED
        }
        asm volatile("s_waitcnt vmcnt(0)" ::: "memory");
        __syncthreads();
    }

    const int rowb = bm * BM + wr * 128;
    const int colb = bn * BN_ + wc * 64;
    float lmax = 0.f;
#pragma unroll
    for (int n = 0; n < NF; ++n) {
        const f32x4 bv = *reinterpret_cast<const f32x4*>(bias + colb + n * 16 + l4 * 4);
#pragma unroll
        for (int m = 0; m < 8; ++m) {
            const int row = rowb + m * 16 + l15;
            bf16x4 o;
#pragma unroll
            for (int r = 0; r < 4; ++r) {
                const float v = acc[m][n][r] + bv[r];
                lmax = fmaxf(lmax, fabsf(v));
                o[r] = (__bf16)v;
            }
            *reinterpret_cast<bf16x4*>(
                &outp[(size_t)row * N + colb + n * 16 + l4 * 4]) = o;
        }
    }
#pragma unroll
    for (int off = 32; off > 0; off >>= 1)
        lmax = fmaxf(lmax, __shfl_down(lmax, off, 64));
    float* wredmax = (float*)lds;
    if (lane == 0) wredmax[wave] = lmax;
    __syncthreads();
    if (tid == 0) {
        float bmax = wredmax[0];
#pragma unroll
        for (int w = 1; w < 8; ++w) bmax = fmaxf(bmax, wredmax[w]);
        atomicMax(gmax + (bm * BM) / 4096, __float_as_uint(bmax));
    }
}

// ================= GEMM2: out[m,n] = y1q[m,:]*W2b[n,:] + b2[n], f32 out =====
// R9 proven structure: gload_lds A+B, T2 swizzle, swap epilogue, f32x4 stores.
__global__ __launch_bounds__(512, 2)
void gemm2_bt(const __bf16* __restrict__ A, const __bf16* __restrict__ Bw,
              const float* __restrict__ bias, float* __restrict__ outp,
              unsigned int* __restrict__ gmax, int M, int N, int K,
              int GN, int nwg) {
    constexpr int BM = 256, BN_ = 128, BK = 64, NF = 2;
    constexpr int ABYTES = BM * BK * 2;
    constexpr int BBYTES = BN_ * BK * 2;
    __shared__ __attribute__((aligned(16))) char lds[2 * (ABYTES + BBYTES)];

    const int tid = threadIdx.x;
    const int wave = tid >> 6, lane = tid & 63;
    const int l15 = lane & 15, l4 = lane >> 4;
    const int wr = wave >> 2, wc = wave & 3;

    const int cpx = nwg >> 3;
    const int orig = (blockIdx.x & 7) * cpx + (blockIdx.x >> 3);
    const int bm = orig / GN, bn = orig % GN;

    const __bf16* Ab = A + (size_t)bm * BM * K;
    const __bf16* Bb = Bw + (size_t)bn * BN_ * K;
    const int NT = K / BK;

    f32x4 acc[8][NF];
#pragma unroll
    for (int m = 0; m < 8; ++m)
#pragma unroll
        for (int n = 0; n < NF; ++n)
            acc[m][n] = f32x4{0.f, 0.f, 0.f, 0.f};

    auto STAGE = [&](int t) {
        const int k0 = t * BK;
        char* ab = lds + (t & 1) * (ABYTES + BBYTES);
        char* bb = ab + ABYTES;
#pragma unroll
        for (int j = 0; j < 4; ++j) {
            const int q = j * 8192 + tid * 16;
            const int lr = q >> 7;
            const int s = ((q >> 4) & 7) ^ (lr & 7);
            gload_lds16(Ab + (size_t)lr * K + k0 + s * 8, ab + q);
        }
#pragma unroll
        for (int j = 0; j < 2; ++j) {
            const int q = j * 8192 + tid * 16;
            const int lr = q >> 7;
            const int s = ((q >> 4) & 7) ^ (lr & 7);
            gload_lds16(Bb + (size_t)lr * K + k0 + s * 8, bb + q);
        }
    };

    STAGE(0);
    asm volatile("s_waitcnt vmcnt(0)" ::: "memory");
    __syncthreads();

    for (int t = 0; t < NT; ++t) {
        if (t + 1 < NT) STAGE(t + 1);
        const char* ab = lds + (t & 1) * (ABYTES + BBYTES);
        const char* bb = ab + ABYTES;
#pragma unroll
        for (int kk = 0; kk < 2; ++kk) {
            bf16x8 af[8], bfv[NF];
#pragma unroll
            for (int m = 0; m < 8; ++m) {
                const int r = wr * 128 + m * 16 + l15;
                const int sp = (kk * 4 + l4) ^ (r & 7);
                af[m] = *reinterpret_cast<const bf16x8*>(ab + r * 128 + sp * 16);
            }
#pragma unroll
            for (int n = 0; n < NF; ++n) {
                const int r = wc * 32 + n * 16 + l15;
                const int sp = (kk * 4 + l4) ^ (r & 7);
                bfv[n] = *reinterpret_cast<const bf16x8*>(bb + r * 128 + sp * 16);
            }
#pragma unroll
            for (int m = 0; m < 8; ++m)
#pragma unroll
                for (int n = 0; n < NF; ++n)
                    acc[m][n] = __builtin_amdgcn_mfma_f32_16x16x32_bf16(
                        bfv[n], af[m], acc[m][n], 0, 0, 0);   // SWAPPED
        }
        asm volatile("s_waitcnt vmcnt(0)" ::: "memory");
        __syncthreads();
    }

    const int rowb = bm * BM + wr * 128;
    const int colb = bn * BN_ + wc * 32;
    float lmax = 0.f;
#pragma unroll
    for (int n = 0; n < NF; ++n) {
        const f32x4 bv = *reinterpret_cast<const f32x4*>(bias + colb + n * 16 + l4 * 4);
#pragma unroll
        for (int m = 0; m < 8; ++m) {
            const int row = rowb + m * 16 + l15;
            f32x4 o;
#pragma unroll
            for (int r = 0; r < 4; ++r) {
                o[r] = acc[m][n][r] + bv[r];
                lmax = fmaxf(lmax, fabsf(o[r]));
            }
            *reinterpret_cast<f32x4*>(
                &outp[(size_t)row * N + colb + n * 16 + l4 * 4]) = o;
        }
    }
#pragma unroll
    for (int off = 32; off > 0; off >>= 1)
        lmax = fmaxf(lmax, __shfl_down(lmax, off, 64));
    float* wredmax = (float*)lds;
    if (lane == 0) wredmax[wave] = lmax;
    __syncthreads();
    if (tid == 0) {
        float bmax = wredmax[0];
#pragma unroll
        for (int w = 1; w < 8; ++w) bmax = fmaxf(bmax, wredmax[w]);
        atomicMax(gmax + (bm * BM) / 4096, __float_as_uint(bmax));
    }
}

// ---------- in-place absmax quantize + FAST exact-GELU, grid-stride ---------
__global__ void quant_gelu(__bf16* __restrict__ y, const unsigned int* __restrict__ gbits,
                           int perg8, int n8) {
    const int stride = gridDim.x * blockDim.x;
    for (int i = blockIdx.x * blockDim.x + threadIdx.x; i < n8; i += stride) {
        const int g = i / perg8;
        const float gamma = __uint_as_float(gbits[g]);
        const float s = 128.0f / (gamma + 1e-5f);
        bf16x8 v = *reinterpret_cast<const bf16x8*>(y + 8 * (size_t)i);
        bf16x8 o;
#pragma unroll
        for (int j = 0; j < 8; ++j) {
            float f = (float)v[j] * s;
            f = fminf(fmaxf(f, -128.0f + 1e-5f), 128.0f - 1e-5f);
            o[j] = (__bf16)gelu_fast(f);
        }
        *reinterpret_cast<bf16x8*>(y + 8 * (size_t)i) = o;
    }
}

// ---------- in-place absmax quantize of f32 output ----------
__global__ void final_scale(float* __restrict__ y, const unsigned int* __restrict__ gbits,
                            int perg4, int n4) {
    int i = blockIdx.x * blockDim.x + threadIdx.x;
    if (i >= n4) return;
    const int g = i / perg4;
    const float gamma = __uint_as_float(gbits[g]);
    const float s = 128.0f / (gamma + 1e-5f);
    f32x4 v = *reinterpret_cast<const f32x4*>(y + 4 * (size_t)i);
    f32x4 o;
#pragma unroll
    for (int j = 0; j < 4; ++j)
        o[j] = fminf(fmaxf(v[j] * s, -128.0f + 1e-5f), 128.0f - 1e-5f);
    *reinterpret_cast<f32x4*>(y + 4 * (size_t)i) = o;
}

extern "C" void kernel_launch(void* const* d_in, const int* in_sizes, int n_in,
                              void* d_out, int out_size, void* d_ws, size_t ws_size,
                              hipStream_t stream) {
    const float* x  = (const float*)d_in[0];   // (10,2048,384)
    const float* W1 = (const float*)d_in[1];   // (1536,384)
    const float* b1 = (const float*)d_in[2];   // (1536,)
    const float* W2 = (const float*)d_in[3];   // (384,1536)
    const float* b2 = (const float*)d_in[4];   // (384,)
    float* out = (float*)d_out;                // (10,2048,384) f32

    const int BB = 10, TT = 2048, C = 384, H = 1536;
    const int M = BB * TT;                     // 20480; act group = 4096 rows

    const int gs1 = H / 5;
    const int gs2 = C / 5;
    const int epg1 = gs1 * C;
    const int epg2 = gs2 * H;
    const int tail1 = (H - 5 * gs1) * C;
    const int tail2 = (C - 5 * gs2) * H;

    const size_t szW1b = (size_t)H * C * 2;
    const size_t szW2b = (size_t)C * H * 2;
    const size_t szXb  = (size_t)M * C * 2;
    const size_t szY1  = (size_t)M * H * 2;

    char* p = (char*)d_ws;
    __bf16* W1b = (__bf16*)p; p += szW1b;
    __bf16* W2b = (__bf16*)p; p += szW2b;
    __bf16* xb  = (__bf16*)p; p += szXb;
    __bf16* y1  = (__bf16*)p; p += szY1;
    unsigned int* gamma = (unsigned int*)p; p += 64;
    float* psums = (float*)p; p += 2 * 5 * NB * 4;
    if ((size_t)(p - (char*)d_ws) > ws_size) return;

    zero_gamma<<<1, 64, 0, stream>>>(gamma);

    group_partial_sums<<<dim3(NB, 5), THREADS, 0, stream>>>(W1, psums, epg1);
    group_partial_sums<<<dim3(NB, 5), THREADS, 0, stream>>>(W2, psums + 5 * NB, epg2);
    binarize_apply<<<dim3(NB, 6), THREADS, 0, stream>>>(W1, W1b, psums, epg1, tail1);
    binarize_apply<<<dim3(NB, 6), THREADS, 0, stream>>>(W2, W2b, psums + 5 * NB, epg2, tail2);

    cvt_f32_bf16<<<(M * C / 4 + THREADS - 1) / THREADS, THREADS, 0, stream>>>(x, xb, M * C / 4);

    // GEMM1: 20480x1536x384. grid 80*6 = 480 (%8==0)
    gemm1_bt<<<480, 512, 0, stream>>>(
        xb, W1b, b1, y1, gamma, M, H, C, H / 256, 480);

    // quant+gelu (fast erf), grid-stride at 2048 blocks
    quant_gelu<<<2048, THREADS, 0, stream>>>(
        y1, gamma, (M / 5) * H / 8, M * H / 8);

    // GEMM2: 20480x384x1536. grid 80*3 = 240 (%8==0)
    gemm2_bt<<<240, 512, 0, stream>>>(
        y1, W2b, b2, out, gamma + 5, M, C, H, C / 128, 240);

    final_scale<<<(M * C / 4 + THREADS - 1) / THREADS, THREADS, 0, stream>>>(
        out, gamma + 5, (M / 5) * C / 4, M * C / 4);
}